// Round 7
// baseline (234.497 us; speedup 1.0000x reference)
//
#include <hip/hip_runtime.h>
#include <math.h>

// Problem constants (from reference)
#define B        32
#define BEAM     5
#define V        128000
#define L        512
#define PAD_IDX  0
#define EOS_IDX  2
#define NROWS    (B * BEAM)          // 160
#define TOPK     10                  // 2*BEAM candidates per sentence

// Phase-1 tiling
#define CHUNK4   4096                        // float4 per chunk
#define ROW4     (V / 4)                     // 32000 float4 per row
#define CPR      8                           // chunks per row
#define FULL_IT  (CHUNK4 / 256)              // 16 iters (full chunk)
#define TAIL4    (ROW4 - (CPR - 1) * CHUNK4) // 3328 float4 in last chunk
#define TAIL_IT  (TAIL4 / 256)               // 13 iters (exact)
#define NBLK1    (NROWS * CPR)               // 1280 blocks
#define P1WAVES  4
#define CAND_PER_SENT (BEAM * CPR * P1WAVES * TOPK)  // 1600 = 64*25
#define NCAND    (B * CAND_PER_SENT)         // 51200
#define WS_NEED  ((size_t)NCAND * 8)         // cand_s + cand_i bytes

#define SENT_I   0x7FFFFFFF

// Guarded insertion into per-thread sorted (desc) top-10.
// Tie-break: equal score -> lower index ranks first (jax.lax.top_k semantics).
// All register indices compile-time constant (runtime idx would go to scratch).
__device__ __forceinline__ void insert10(float v, int idx,
                                         float (&ts)[TOPK], int (&ti)[TOPK]) {
    if (!((v > ts[TOPK - 1]) || (v == ts[TOPK - 1] && idx < ti[TOPK - 1]))) return;
    float cv = v; int ci = idx;
#pragma unroll
    for (int j = 0; j < TOPK; ++j) {
        bool gt = (cv > ts[j]) || (cv == ts[j] && ci < ti[j]);
        float tv = ts[j]; int tj = ti[j];
        if (gt) { ts[j] = cv; ti[j] = ci; cv = tv; ci = tj; }
    }
}

// Robust cur_len decode: int32 / little-endian int64 / float32 encodings.
__device__ __forceinline__ int decode_len(const int* p) {
    int v = p[0];
    if ((unsigned)v < (unsigned)L) return v;
    float f = __int_as_float(v);
    int fi_ = (int)f;
    if (f == (float)fi_ && (unsigned)fi_ < (unsigned)L) return fi_;
    return v & (L - 1);
}

// ---------------- Fast path: phase 1 ----------------
// One block per (row, chunk). Scans RAW scores: within-row ordering is
// invariant under +beam_score; bs added at emit with the same f32 add the
// reference does -> emitted candidate scores bit-identical to reference comb.
__global__ __launch_bounds__(256) void p1_scan_topk(
    const float* __restrict__ scores,       // [NROWS, V]
    const float* __restrict__ beam_scores,  // [NROWS]
    float* __restrict__ cand_s,             // [NCAND]
    int*   __restrict__ cand_i)             // [NCAND]
{
    const int bid   = blockIdx.x;
    const int row   = bid >> 3;             // bid / CPR
    const int chunk = bid & 7;              // bid % CPR
    const int beam  = row % BEAM;

    const float4* p = (const float4*)(scores + (size_t)row * V)
                      + chunk * CHUNK4 + threadIdx.x;
    const int e0 = (chunk * CHUNK4 + (int)threadIdx.x) * 4;

    float ts[TOPK]; int ti[TOPK];
#pragma unroll
    for (int j = 0; j < TOPK; ++j) { ts[j] = -INFINITY; ti[j] = SENT_I; }

    const int iters = (chunk == CPR - 1) ? TAIL_IT : FULL_IT;  // block-uniform
    for (int it = 0; it < iters; ++it) {
        float4 f = p[it * 256];
        float m = fmaxf(fmaxf(f.x, f.y), fmaxf(f.z, f.w));
        if (m >= ts[TOPK - 1]) {            // rare after warm-up
            int e = e0 + it * 1024;
            insert10(f.x, e,     ts, ti);
            insert10(f.y, e + 1, ts, ti);
            insert10(f.z, e + 2, ts, ti);
            insert10(f.w, e + 3, ts, ti);
        }
    }

    const int lane    = threadIdx.x & 63;
    const int waveid  = threadIdx.x >> 6;
    const int outbase = (bid * P1WAVES + waveid) * TOPK;
    const float bs    = beam_scores[row];
    const int idx_base = beam * V;

    for (int k = 0; k < TOPK; ++k) {
        float v = ts[0]; int idx = ti[0]; int who = lane;
#pragma unroll
        for (int off = 1; off < 64; off <<= 1) {
            float ov = __shfl_xor(v, off);
            int   oi = __shfl_xor(idx, off);
            int   ow = __shfl_xor(who, off);
            if ((ov > v) || (ov == v && oi < idx)) { v = ov; idx = oi; who = ow; }
        }
        if (lane == 0) {
            cand_s[outbase + k] = v + bs;          // exact reference comb value
            cand_i[outbase + k] = idx_base + idx;  // comb index beam*V + word
        }
        if (lane == who) {  // winner pops its head (static-index shift)
#pragma unroll
            for (int j = 0; j < TOPK - 1; ++j) { ts[j] = ts[j + 1]; ti[j] = ti[j + 1]; }
            ts[TOPK - 1] = -INFINITY; ti[TOPK - 1] = SENT_I;
        }
    }
}

// ---------------- Fast path: phase 2 ----------------
// One block per sentence. Single-wave merge of 1600 candidates -> sorted
// top-10, EOS filter, then 256-thread FLOAT32 gather/write.
// d_out is float32: [NROWS*L] new_generated tokens (as floats), then
// [B*BEAM] sel_scores. (Harness bf16-truncates both sides for comparison.)
__global__ __launch_bounds__(256) void p2_merge_select(
    const float* __restrict__ cand_s,
    const int*   __restrict__ cand_i,
    const int*   __restrict__ generated,    // [NROWS, L] int32
    const int*   __restrict__ cur_len_p,    // [1]
    float* __restrict__ out_f32)            // [NROWS*L + B*BEAM] f32
{
    const int b   = blockIdx.x;
    const int tid = threadIdx.x;

    __shared__ float fs[TOPK];
    __shared__ int   fi[TOPK];
    __shared__ int   sh_word[BEAM], sh_src[BEAM];
    __shared__ int   sh_cur;

    if (tid < 64) {                          // single-wave merge
        float ts[TOPK]; int ti[TOPK];
#pragma unroll
        for (int j = 0; j < TOPK; ++j) { ts[j] = -INFINITY; ti[j] = SENT_I; }

        const float* cs = cand_s + b * CAND_PER_SENT;
        const int*   ci = cand_i + b * CAND_PER_SENT;
#pragma unroll
        for (int i = 0; i < CAND_PER_SENT / 64; ++i)   // 25 per lane
            insert10(cs[tid + 64 * i], ci[tid + 64 * i], ts, ti);

        for (int k = 0; k < TOPK; ++k) {
            float v = ts[0]; int idx = ti[0]; int who = tid;
#pragma unroll
            for (int off = 1; off < 64; off <<= 1) {
                float ov = __shfl_xor(v, off);
                int   oi = __shfl_xor(idx, off);
                int   ow = __shfl_xor(who, off);
                if ((ov > v) || (ov == v && oi < idx)) { v = ov; idx = oi; who = ow; }
            }
            if (tid == 0) { fs[k] = v; fi[k] = idx; }
            if (tid == who) {
#pragma unroll
                for (int j = 0; j < TOPK - 1; ++j) { ts[j] = ts[j + 1]; ti[j] = ti[j + 1]; }
                ts[TOPK - 1] = -INFINITY; ti[TOPK - 1] = SENT_I;
            }
        }

        if (tid == 0) {
            sh_cur = decode_len(cur_len_p);
            int cnt = 0;
            for (int k = 0; k < TOPK && cnt < BEAM; ++k) {
                int idx  = fi[k];
                int bm   = idx / V;
                int word = idx - bm * V;
                if (word != EOS_IDX) {
                    sh_word[cnt] = word;
                    sh_src[cnt]  = b * BEAM + bm;   // eff_beam (global row id)
                    out_f32[NROWS * L + b * BEAM + cnt] = fs[k];
                    ++cnt;
                }
            }
            for (; cnt < BEAM; ++cnt) {             // fallback slots
                sh_word[cnt] = PAD_IDX;
                sh_src[cnt]  = 0;                   // reference: eff_beam = 0 (GLOBAL row 0)
                out_f32[NROWS * L + b * BEAM + cnt] = 0.0f;
            }
        }
    }
    __syncthreads();

    // reorder hypotheses + append word at column cur; f32 stores (coalesced)
    const int cur = sh_cur;
    for (int i = tid; i < BEAM * L; i += 256) {
        int slot = i >> 9;                   // i / L
        int col  = i & (L - 1);              // i % L
        int val  = (col == cur) ? sh_word[slot]
                                : generated[sh_src[slot] * L + col];
        out_f32[(b * BEAM + slot) * L + col] = (float)val;  // ints<2^24 exact
    }
}

// ---------------- Fallback: single self-contained kernel (no workspace) ----
__global__ __launch_bounds__(1024) void beam_step_fb(
    const float* __restrict__ scores,
    const float* __restrict__ beam_scores,
    const int*   __restrict__ generated,
    const int*   __restrict__ cur_len_p,
    float* __restrict__ out_f32)
{
    const int b    = blockIdx.x;
    const int tid  = threadIdx.x;
    const int lane = tid & 63;
    const int wave = tid >> 6;

    __shared__ float cs[16 * TOPK];
    __shared__ int   ci[16 * TOPK];
    __shared__ float fs[TOPK];
    __shared__ int   fi[TOPK];
    __shared__ int   sh_word[BEAM], sh_src[BEAM];
    __shared__ int   sh_cur;

    float ts[TOPK]; int ti[TOPK];
#pragma unroll
    for (int j = 0; j < TOPK; ++j) { ts[j] = -INFINITY; ti[j] = SENT_I; }

    for (int beam = 0; beam < BEAM; ++beam) {
        const float   bs = beam_scores[b * BEAM + beam];
        const float4* p  = (const float4*)(scores + (size_t)(b * BEAM + beam) * V);
        const int     ib = beam * V;
        for (int j4 = tid; j4 < ROW4; j4 += 1024) {
            float4 f = p[j4];
            float x = f.x + bs, y = f.y + bs, z = f.z + bs, w = f.w + bs;
            float m = fmaxf(fmaxf(x, y), fmaxf(z, w));
            if (m >= ts[TOPK - 1]) {
                int e = ib + j4 * 4;
                insert10(x, e, ts, ti); insert10(y, e + 1, ts, ti);
                insert10(z, e + 2, ts, ti); insert10(w, e + 3, ts, ti);
            }
        }
    }
    for (int k = 0; k < TOPK; ++k) {
        float v = ts[0]; int idx = ti[0]; int who = lane;
#pragma unroll
        for (int off = 1; off < 64; off <<= 1) {
            float ov = __shfl_xor(v, off); int oi = __shfl_xor(idx, off);
            int ow = __shfl_xor(who, off);
            if ((ov > v) || (ov == v && oi < idx)) { v = ov; idx = oi; who = ow; }
        }
        if (lane == 0) { cs[wave * TOPK + k] = v; ci[wave * TOPK + k] = idx; }
        if (lane == who) {
#pragma unroll
            for (int j = 0; j < TOPK - 1; ++j) { ts[j] = ts[j + 1]; ti[j] = ti[j + 1]; }
            ts[TOPK - 1] = -INFINITY; ti[TOPK - 1] = SENT_I;
        }
    }
    __syncthreads();
    if (wave == 0) {
#pragma unroll
        for (int j = 0; j < TOPK; ++j) { ts[j] = -INFINITY; ti[j] = SENT_I; }
        for (int i = lane; i < 16 * TOPK; i += 64) insert10(cs[i], ci[i], ts, ti);
        for (int k = 0; k < TOPK; ++k) {
            float v = ts[0]; int idx = ti[0]; int who = lane;
#pragma unroll
            for (int off = 1; off < 64; off <<= 1) {
                float ov = __shfl_xor(v, off); int oi = __shfl_xor(idx, off);
                int ow = __shfl_xor(who, off);
                if ((ov > v) || (ov == v && oi < idx)) { v = ov; idx = oi; who = ow; }
            }
            if (lane == 0) { fs[k] = v; fi[k] = idx; }
            if (lane == who) {
#pragma unroll
                for (int j = 0; j < TOPK - 1; ++j) { ts[j] = ts[j + 1]; ti[j] = ti[j + 1]; }
                ts[TOPK - 1] = -INFINITY; ti[TOPK - 1] = SENT_I;
            }
        }
        if (lane == 0) {
            sh_cur = decode_len(cur_len_p);
            int cnt = 0;
            for (int k = 0; k < TOPK && cnt < BEAM; ++k) {
                int idx = fi[k]; int bm = idx / V; int word = idx - bm * V;
                if (word != EOS_IDX) {
                    sh_word[cnt] = word; sh_src[cnt] = b * BEAM + bm;
                    out_f32[NROWS * L + b * BEAM + cnt] = fs[k];
                    ++cnt;
                }
            }
            for (; cnt < BEAM; ++cnt) {
                sh_word[cnt] = PAD_IDX; sh_src[cnt] = 0;
                out_f32[NROWS * L + b * BEAM + cnt] = 0.0f;
            }
        }
    }
    __syncthreads();
    const int cur = sh_cur;
    for (int i = tid; i < BEAM * L; i += 1024) {
        int slot = i >> 9; int col = i & (L - 1);
        int val = (col == cur) ? sh_word[slot]
                               : generated[sh_src[slot] * L + col];
        out_f32[(b * BEAM + slot) * L + col] = (float)val;
    }
}

extern "C" void kernel_launch(void* const* d_in, const int* in_sizes, int n_in,
                              void* d_out, int out_size, void* d_ws, size_t ws_size,
                              hipStream_t stream) {
    // Size-based input dispatch (all element counts distinct).
    const float* scores      = nullptr;
    const float* beam_scores = nullptr;
    const int*   generated   = nullptr;
    const int*   cur_len_p   = nullptr;
    for (int i = 0; i < n_in; ++i) {
        switch (in_sizes[i]) {
            case NROWS * V:  scores      = (const float*)d_in[i]; break; // 20480000
            case NROWS:      beam_scores = (const float*)d_in[i]; break; // 160
            case NROWS * L:  generated   = (const int*)d_in[i];   break; // 81920
            case 1:          cur_len_p   = (const int*)d_in[i];   break; // 1
            default: break;
        }
    }
    if (!scores)      scores      = (const float*)d_in[0];
    if (!beam_scores) beam_scores = (const float*)d_in[1];
    if (!generated)   generated   = (const int*)d_in[2];
    if (!cur_len_p)   cur_len_p   = (const int*)d_in[3];

    // d_out is FLOAT32 (non-bf16 reference outputs -> float*):
    // [160*512] new_generated token values, then [32*5] sel_scores.
    float* out_f32 = (float*)d_out;

    if (ws_size >= WS_NEED) {
        float* cand_s = (float*)d_ws;                    // NCAND f32
        int*   cand_i = (int*)((float*)d_ws + NCAND);    // NCAND i32
        p1_scan_topk<<<NBLK1, 256, 0, stream>>>(scores, beam_scores, cand_s, cand_i);
        p2_merge_select<<<B, 256, 0, stream>>>(cand_s, cand_i, generated, cur_len_p,
                                               out_f32);
    } else {
        beam_step_fb<<<B, 1024, 0, stream>>>(scores, beam_scores, generated,
                                             cur_len_p, out_f32);
    }
}

// Round 10
// 193.020 us; speedup vs baseline: 1.2149x; 1.2149x over previous
//
#include <hip/hip_runtime.h>
#include <math.h>

// Problem constants (from reference)
#define B        32
#define BEAM     5
#define V        128000
#define L        512
#define PAD_IDX  0
#define EOS_IDX  2
#define NROWS    (B * BEAM)          // 160
#define TOPK     10                  // 2*BEAM candidates per sentence

// Kernel-B tiling
#define CHUNK4   4096                        // float4 per chunk
#define ROW4     (V / 4)                     // 32000 float4 per row
#define CPR      8                           // chunks per row
#define FULL_IT  (CHUNK4 / 256)              // 16 iters
#define TAIL4    (ROW4 - (CPR - 1) * CHUNK4) // 3328 float4
#define TAIL_IT  (TAIL4 / 256)               // 13 iters (exact)
#define NBLK1    (NROWS * CPR)               // 1280 blocks
#define P1WAVES  4
#define CAND_PER_SENT (BEAM * CPR * P1WAVES * TOPK)  // 1600
#define NCAND    (B * CAND_PER_SENT)         // 51200

// Kernel-A sampling: first SAMP4 float4 of each row (iid data -> prefix is fine)
#define SAMP4    1024                        // 4096 elements/row, 20480/sentence

// ws layout: theta[64] floats (256 B) | cand_s[NCAND] f32 | cand_i[NCAND] i32
#define WS_NEED  (256 + (size_t)NCAND * 8)

#define SENT_I   0x7FFFFFFF

// ---- helpers ----------------------------------------------------------------

// (score,idx) sorted-desc insert, tie -> lower idx first (jax.lax.top_k order).
// Static indices only (runtime-indexed reg arrays spill to scratch).
__device__ __forceinline__ void insert10(float v, int idx,
                                         float (&ts)[TOPK], int (&ti)[TOPK]) {
    if (!((v > ts[TOPK - 1]) || (v == ts[TOPK - 1] && idx < ti[TOPK - 1]))) return;
    float cv = v; int ci = idx;
#pragma unroll
    for (int j = 0; j < TOPK; ++j) {
        bool gt = (cv > ts[j]) || (cv == ts[j] && ci < ti[j]);
        float tv = ts[j]; int tj = ti[j];
        if (gt) { ts[j] = cv; ti[j] = ci; cv = tv; ci = tj; }
    }
}

__device__ __forceinline__ void popPair(float (&ts)[TOPK], int (&ti)[TOPK]) {
#pragma unroll
    for (int j = 0; j < TOPK - 1; ++j) { ts[j] = ts[j + 1]; ti[j] = ti[j + 1]; }
    ts[TOPK - 1] = -INFINITY; ti[TOPK - 1] = SENT_I;
}

// values-only insert with >= (keeps duplicate values so theta stays a valid
// lower bound of the true 10th-largest)
__device__ __forceinline__ void insV(float v, float (&ts)[TOPK]) {
    if (v < ts[TOPK - 1]) return;
    float cv = v;
#pragma unroll
    for (int j = 0; j < TOPK; ++j) {
        float t = ts[j];
        bool ge = (cv >= t);
        ts[j] = ge ? cv : t;
        cv    = ge ? t : cv;
    }
}

__device__ __forceinline__ void popVal(float (&ts)[TOPK]) {
#pragma unroll
    for (int j = 0; j < TOPK - 1; ++j) ts[j] = ts[j + 1];
    ts[TOPK - 1] = -INFINITY;
}

// Robust cur_len decode: int32 / little-endian int64 / float32 encodings.
__device__ __forceinline__ int decode_len(const int* p) {
    int v = p[0];
    if ((unsigned)v < (unsigned)L) return v;
    float f = __int_as_float(v);
    int fi_ = (int)f;
    if (f == (float)fi_ && (unsigned)fi_ < (unsigned)L) return fi_;
    return v & (L - 1);
}

// ---- Kernel A: per-sentence threshold from a 20480-element sample -----------
// theta_b = 10th largest sampled comb value. Sample subset-of-full =>
// theta_b <= true sentence 10th  => guard in B can never drop a true top-10.
// Dup-pops in the tournaments only shrink theta further (safe direction).
__global__ __launch_bounds__(256, 4) void a_theta(
    const float* __restrict__ scores,
    const float* __restrict__ beam_scores,
    float* __restrict__ theta)              // [B]
{
    const int b    = blockIdx.x;
    const int tid  = threadIdx.x;
    const int lane = tid & 63;
    const int wave = tid >> 6;

    float ts[TOPK];
#pragma unroll
    for (int j = 0; j < TOPK; ++j) ts[j] = -INFINITY;

    for (int r = 0; r < BEAM; ++r) {
        const int row = b * BEAM + r;
        const float bs = beam_scores[row];
        const float4* p = (const float4*)(scores + (size_t)row * V);
#pragma unroll
        for (int it = 0; it < SAMP4 / 256; ++it) {   // 4 iters
            float4 f = p[it * 256 + tid];
            insV(f.x + bs, ts); insV(f.y + bs, ts);
            insV(f.z + bs, ts); insV(f.w + bs, ts);
        }
    }

    __shared__ float wtop[4][TOPK];
    for (int k = 0; k < TOPK; ++k) {         // wave top-10 (values only)
        float v = ts[0];
#pragma unroll
        for (int off = 1; off < 64; off <<= 1) v = fmaxf(v, __shfl_xor(v, off));
        if (lane == 0) wtop[wave][k] = v;
        if (ts[0] == v) popVal(ts);          // dup-pop: conservative-safe
    }
    __syncthreads();
    if (wave == 0) {
        float v0 = (lane < 4 * TOPK) ? wtop[lane / TOPK][lane % TOPK] : -INFINITY;
        float th = -INFINITY;
        for (int k = 0; k < TOPK; ++k) {
            float v = v0;
#pragma unroll
            for (int off = 1; off < 64; off <<= 1) v = fmaxf(v, __shfl_xor(v, off));
            th = v;
            if (v0 == v) v0 = -INFINITY;
        }
        if (lane == 0) theta[b] = th;
    }
}

// ---- Kernel B: streaming scan with sentence-global threshold guard ----------
// Guard safety: m = max of 4 raw; fl monotone => fl(m+bs) >= fl(x+bs) for any
// of the 4 => testing fl(m+bs) >= theta can never skip an element whose comb
// >= theta. comb computed with the exact reference f32 add at insert time.
__global__ __launch_bounds__(256, 4) void b_scan(
    const float* __restrict__ scores,       // [NROWS, V]
    const float* __restrict__ beam_scores,  // [NROWS]
    const float* __restrict__ theta,        // [B]
    float* __restrict__ cand_s,             // [NCAND]
    int*   __restrict__ cand_i)             // [NCAND]
{
    const int bid   = blockIdx.x;
    const int row   = bid >> 3;
    const int chunk = bid & 7;
    const int beam  = row % BEAM;
    const float bs  = beam_scores[row];
    const float th  = theta[row / BEAM];

    const float4* p = (const float4*)(scores + (size_t)row * V)
                      + chunk * CHUNK4 + threadIdx.x;
    const int e0 = (chunk * CHUNK4 + (int)threadIdx.x) * 4 + beam * V;

    float ts[TOPK]; int ti[TOPK];
#pragma unroll
    for (int j = 0; j < TOPK; ++j) { ts[j] = -INFINITY; ti[j] = SENT_I; }

    const int iters = (chunk == CPR - 1) ? TAIL_IT : FULL_IT;  // block-uniform
    for (int it = 0; it < iters; ++it) {
        float4 f = p[it * 256];
        float m = fmaxf(fmaxf(f.x, f.y), fmaxf(f.z, f.w));
        if (m + bs >= th) {                  // rare: ~312 hits/sentence total
            int e = e0 + it * 1024;
            insert10(f.x + bs, e,     ts, ti);
            insert10(f.y + bs, e + 1, ts, ti);
            insert10(f.z + bs, e + 2, ts, ti);
            insert10(f.w + bs, e + 3, ts, ti);
        }
    }

    const int lane    = threadIdx.x & 63;
    const int wv      = threadIdx.x >> 6;
    const int outbase = (bid * P1WAVES + wv) * TOPK;

    int k = 0;
    for (; k < TOPK; ++k) {                  // wave tournament, early break
        float v = ts[0]; int idx = ti[0];
#pragma unroll
        for (int off = 1; off < 64; off <<= 1) {
            float ov = __shfl_xor(v, off);
            int   oi = __shfl_xor(idx, off);
            if ((ov > v) || (ov == v && oi < idx)) { v = ov; idx = oi; }
        }
        if (v == -INFINITY) break;           // wave-uniform
        if (lane == 0) { cand_s[outbase + k] = v; cand_i[outbase + k] = idx; }
        if (ts[0] == v && ti[0] == idx) popPair(ts, ti);  // idx unique -> 1 lane
    }
    if (lane >= k && lane < TOPK) {          // pad (ws is poisoned 0xAA)
        cand_s[outbase + lane] = -INFINITY;
        cand_i[outbase + lane] = SENT_I;
    }
}

// ---- Kernel C: merge 1600 candidates, EOS filter, write outputs -------------
__global__ __launch_bounds__(256, 4) void c_select(
    const float* __restrict__ cand_s,
    const int*   __restrict__ cand_i,
    const int*   __restrict__ generated,    // [NROWS, L] int32
    const int*   __restrict__ cur_len_p,    // [1]
    float* __restrict__ out_f32)            // [NROWS*L] tokens, then [B*BEAM] scores
{
    const int b    = blockIdx.x;
    const int tid  = threadIdx.x;
    const int lane = tid & 63;
    const int wave = tid >> 6;

    __shared__ float swv[4][TOPK];
    __shared__ int   swi[4][TOPK];
    __shared__ float fs[TOPK];
    __shared__ int   fi[TOPK];
    __shared__ int   sh_word[BEAM], sh_src[BEAM];
    __shared__ int   sh_cur;

    float ts[TOPK]; int ti[TOPK];
#pragma unroll
    for (int j = 0; j < TOPK; ++j) { ts[j] = -INFINITY; ti[j] = SENT_I; }

    const int base = b * CAND_PER_SENT;
    for (int i = tid; i < CAND_PER_SENT; i += 256)      // ~6-7 per thread
        insert10(cand_s[base + i], cand_i[base + i], ts, ti);

    int k = 0;
    for (; k < TOPK; ++k) {                  // per-wave tournament, early break
        float v = ts[0]; int idx = ti[0];
#pragma unroll
        for (int off = 1; off < 64; off <<= 1) {
            float ov = __shfl_xor(v, off);
            int   oi = __shfl_xor(idx, off);
            if ((ov > v) || (ov == v && oi < idx)) { v = ov; idx = oi; }
        }
        if (v == -INFINITY) break;
        if (lane == 0) { swv[wave][k] = v; swi[wave][k] = idx; }
        if (ts[0] == v && ti[0] == idx) popPair(ts, ti);
    }
    if (lane >= k && lane < TOPK) {
        swv[wave][lane] = -INFINITY; swi[wave][lane] = SENT_I;
    }
    __syncthreads();

    if (wave == 0) {                         // final merge of 40 pairs
        float v0; int i0;
        if (lane < 4 * TOPK) { v0 = swv[lane / TOPK][lane % TOPK];
                               i0 = swi[lane / TOPK][lane % TOPK]; }
        else                 { v0 = -INFINITY; i0 = SENT_I; }
        for (int r = 0; r < TOPK; ++r) {
            float v = v0; int idx = i0;
#pragma unroll
            for (int off = 1; off < 64; off <<= 1) {
                float ov = __shfl_xor(v, off);
                int   oi = __shfl_xor(idx, off);
                if ((ov > v) || (ov == v && oi < idx)) { v = ov; idx = oi; }
            }
            if (lane == 0) { fs[r] = v; fi[r] = idx; }
            if (v0 == v && i0 == idx) { v0 = -INFINITY; i0 = SENT_I; }
        }
        if (lane == 0) {                     // EOS filter (same thread wrote fs/fi)
            sh_cur = decode_len(cur_len_p);
            int cnt = 0;
            for (int kk = 0; kk < TOPK && cnt < BEAM; ++kk) {
                int idx  = fi[kk];
                int bm   = idx / V;
                int word = idx - bm * V;
                if (word != EOS_IDX) {
                    sh_word[cnt] = word;
                    sh_src[cnt]  = b * BEAM + bm;    // eff_beam (global row id)
                    out_f32[NROWS * L + b * BEAM + cnt] = fs[kk];
                    ++cnt;
                }
            }
            for (; cnt < BEAM; ++cnt) {              // fallback slots
                sh_word[cnt] = PAD_IDX;
                sh_src[cnt]  = 0;                    // reference: GLOBAL row 0
                out_f32[NROWS * L + b * BEAM + cnt] = 0.0f;
            }
        }
    }
    __syncthreads();

    const int cur = sh_cur;                  // gather + append (f32 tokens exact)
    for (int i = tid; i < BEAM * L; i += 256) {
        int slot = i >> 9;
        int col  = i & (L - 1);
        int val  = (col == cur) ? sh_word[slot]
                                : generated[sh_src[slot] * L + col];
        out_f32[(b * BEAM + slot) * L + col] = (float)val;
    }
}

// ---- Fallback: self-contained single kernel (no workspace) ------------------
__global__ __launch_bounds__(1024) void beam_step_fb(
    const float* __restrict__ scores,
    const float* __restrict__ beam_scores,
    const int*   __restrict__ generated,
    const int*   __restrict__ cur_len_p,
    float* __restrict__ out_f32)
{
    const int b    = blockIdx.x;
    const int tid  = threadIdx.x;
    const int lane = tid & 63;
    const int wave = tid >> 6;

    __shared__ float cs[16 * TOPK];
    __shared__ int   ci[16 * TOPK];
    __shared__ float fs[TOPK];
    __shared__ int   fi[TOPK];
    __shared__ int   sh_word[BEAM], sh_src[BEAM];
    __shared__ int   sh_cur;

    float ts[TOPK]; int ti[TOPK];
#pragma unroll
    for (int j = 0; j < TOPK; ++j) { ts[j] = -INFINITY; ti[j] = SENT_I; }

    for (int beam = 0; beam < BEAM; ++beam) {
        const float   bs = beam_scores[b * BEAM + beam];
        const float4* p  = (const float4*)(scores + (size_t)(b * BEAM + beam) * V);
        const int     ib = beam * V;
        for (int j4 = tid; j4 < ROW4; j4 += 1024) {
            float4 f = p[j4];
            float x = f.x + bs, y = f.y + bs, z = f.z + bs, w = f.w + bs;
            float m = fmaxf(fmaxf(x, y), fmaxf(z, w));
            if (m >= ts[TOPK - 1]) {
                int e = ib + j4 * 4;
                insert10(x, e, ts, ti); insert10(y, e + 1, ts, ti);
                insert10(z, e + 2, ts, ti); insert10(w, e + 3, ts, ti);
            }
        }
    }
    for (int k = 0; k < TOPK; ++k) {
        float v = ts[0]; int idx = ti[0];
#pragma unroll
        for (int off = 1; off < 64; off <<= 1) {
            float ov = __shfl_xor(v, off); int oi = __shfl_xor(idx, off);
            if ((ov > v) || (ov == v && oi < idx)) { v = ov; idx = oi; }
        }
        if (lane == 0) { cs[wave * TOPK + k] = v; ci[wave * TOPK + k] = idx; }
        if (ts[0] == v && ti[0] == idx) popPair(ts, ti);
    }
    __syncthreads();
    if (wave == 0) {
#pragma unroll
        for (int j = 0; j < TOPK; ++j) { ts[j] = -INFINITY; ti[j] = SENT_I; }
        for (int i = lane; i < 16 * TOPK; i += 64) insert10(cs[i], ci[i], ts, ti);
        for (int k = 0; k < TOPK; ++k) {
            float v = ts[0]; int idx = ti[0];
#pragma unroll
            for (int off = 1; off < 64; off <<= 1) {
                float ov = __shfl_xor(v, off); int oi = __shfl_xor(idx, off);
                if ((ov > v) || (ov == v && oi < idx)) { v = ov; idx = oi; }
            }
            if (lane == 0) { fs[k] = v; fi[k] = idx; }
            if (ts[0] == v && ti[0] == idx) popPair(ts, ti);
        }
        if (lane == 0) {
            sh_cur = decode_len(cur_len_p);
            int cnt = 0;
            for (int k = 0; k < TOPK && cnt < BEAM; ++k) {
                int idx = fi[k]; int bm = idx / V; int word = idx - bm * V;
                if (word != EOS_IDX) {
                    sh_word[cnt] = word; sh_src[cnt] = b * BEAM + bm;
                    out_f32[NROWS * L + b * BEAM + cnt] = fs[k];
                    ++cnt;
                }
            }
            for (; cnt < BEAM; ++cnt) {
                sh_word[cnt] = PAD_IDX; sh_src[cnt] = 0;
                out_f32[NROWS * L + b * BEAM + cnt] = 0.0f;
            }
        }
    }
    __syncthreads();
    const int cur = sh_cur;
    for (int i = tid; i < BEAM * L; i += 1024) {
        int slot = i >> 9; int col = i & (L - 1);
        int val = (col == cur) ? sh_word[slot]
                               : generated[sh_src[slot] * L + col];
        out_f32[(b * BEAM + slot) * L + col] = (float)val;
    }
}

extern "C" void kernel_launch(void* const* d_in, const int* in_sizes, int n_in,
                              void* d_out, int out_size, void* d_ws, size_t ws_size,
                              hipStream_t stream) {
    // Size-based input dispatch (all element counts distinct).
    const float* scores      = nullptr;
    const float* beam_scores = nullptr;
    const int*   generated   = nullptr;
    const int*   cur_len_p   = nullptr;
    for (int i = 0; i < n_in; ++i) {
        switch (in_sizes[i]) {
            case NROWS * V:  scores      = (const float*)d_in[i]; break; // 20480000
            case NROWS:      beam_scores = (const float*)d_in[i]; break; // 160
            case NROWS * L:  generated   = (const int*)d_in[i];   break; // 81920
            case 1:          cur_len_p   = (const int*)d_in[i];   break; // 1
            default: break;
        }
    }
    if (!scores)      scores      = (const float*)d_in[0];
    if (!beam_scores) beam_scores = (const float*)d_in[1];
    if (!generated)   generated   = (const int*)d_in[2];
    if (!cur_len_p)   cur_len_p   = (const int*)d_in[3];

    // d_out is FLOAT32: [160*512] new_generated token values, then [32*5] scores.
    float* out_f32 = (float*)d_out;

    if (ws_size >= WS_NEED) {
        float* theta  = (float*)d_ws;                          // 64 floats (256 B)
        float* cand_s = (float*)((char*)d_ws + 256);           // NCAND f32
        int*   cand_i = (int*)((char*)d_ws + 256 + (size_t)NCAND * 4);
        a_theta<<<B, 256, 0, stream>>>(scores, beam_scores, theta);
        b_scan<<<NBLK1, 256, 0, stream>>>(scores, beam_scores, theta,
                                          cand_s, cand_i);
        c_select<<<B, 256, 0, stream>>>(cand_s, cand_i, generated, cur_len_p,
                                        out_f32);
    } else {
        beam_step_fb<<<B, 1024, 0, stream>>>(scores, beam_scores, generated,
                                             cur_len_p, out_f32);
    }
}